// Round 16
// baseline (112.013 us; speedup 1.0000x reference)
//
#include <hip/hip_runtime.h>
#include <hip/hip_bf16.h>
#include <math.h>

typedef short bf16x8 __attribute__((ext_vector_type(8)));
typedef _Float16 f16x8 __attribute__((ext_vector_type(8)));
typedef float f32x4 __attribute__((ext_vector_type(4)));
typedef _Float16 h2 __attribute__((ext_vector_type(2)));

__device__ inline short f2bf(float f) {
    union { float f; unsigned u; } v; v.f = f;
    unsigned r = v.u + 0x7FFFu + ((v.u >> 16) & 1u);
    return (short)(r >> 16);
}
__device__ inline float bf2f(short s) {
    union { unsigned u; float f; } v; v.u = ((unsigned)(unsigned short)s) << 16;
    return v.f;
}
__device__ inline h2 pkrtz(float a, float b) {
    return __builtin_bit_cast(h2, __builtin_amdgcn_cvt_pkrtz(a, b));
}
__device__ inline float fast_exp2(float x) {
    float r;
    asm("v_exp_f32 %0, %1" : "=v"(r) : "v"(x));
    return r;
}
__device__ inline float dot2(h2 a, h2 b) {
#if __has_builtin(__builtin_amdgcn_fdot2)
    return __builtin_amdgcn_fdot2(a, b, 0.f, false);
#else
    return (float)a[0] * (float)b[0] + (float)a[1] * (float)b[1];
#endif
}
__device__ inline void nt_store4(float4 v, float* p) {
    __builtin_nontemporal_store(__builtin_bit_cast(f32x4, v), (f32x4*)p);
}

// ---------------------------------------------------------------------------
// z<4: transpose-cast x -> xt [b][p][c] bf16.  z==4: weight cast.
// z==5 (x<8,y==0): per-head 64x64 QUAD RPE table (4 bilinear taps packed as
// 4xf16 in 8B, pre-scaled by log2e).
// ---------------------------------------------------------------------------
__global__ __launch_bounds__(256) void prep_x(
    const float* __restrict__ x, short* __restrict__ xt,
    const float* __restrict__ qw, const float* __restrict__ kw,
    const float* __restrict__ vw, short* __restrict__ qwb,
    short* __restrict__ kwb, short* __restrict__ vwb,
    const float* __restrict__ rpe, uint2* __restrict__ rpet)
{
    __shared__ float ts[64][65];
    int t = threadIdx.x;
    if (blockIdx.z == 5) {   // quad RPE plane: head = blockIdx.x
        if (blockIdx.y != 0 || blockIdx.x >= 8) return;
        int hh = blockIdx.x;
        const float* rh = rpe + hh * 3969;
        const float L2E = 1.44269504f;
        auto P = [&](int y, int xx) -> float {
            return (y >= 1 && y <= 63 && xx >= 1 && xx <= 63)
                 ? rh[(y - 1) * 63 + (xx - 1)] * L2E : 0.f;
        };
        #pragma unroll
        for (int i = 0; i < 16; ++i) {
            int j = i * 256 + t;          // j < 4096
            int qy = j >> 6, qx = j & 63;
            h2 lo, hi;
            lo[0] = (_Float16)P(qy, qx);     lo[1] = (_Float16)P(qy, qx + 1);
            hi[0] = (_Float16)P(qy + 1, qx); hi[1] = (_Float16)P(qy + 1, qx + 1);
            uint2 w;
            w.x = __builtin_bit_cast(unsigned, lo);
            w.y = __builtin_bit_cast(unsigned, hi);
            rpet[hh * 4096 + j] = w;
        }
        return;
    }
    if (blockIdx.z == 4) {   // weight cast plane
        int f = blockIdx.y * 16 + blockIdx.x;
        int base = (f * 256 + t) * 8;
        #pragma unroll
        for (int w = 0; w < 3; ++w) {
            const float* src = (w == 0) ? qw : (w == 1) ? kw : vw;
            short* dst = (w == 0) ? qwb : (w == 1) ? kwb : vwb;
            float4 f0 = *(const float4*)(src + base);
            float4 f1 = *(const float4*)(src + base + 4);
            bf16x8 o;
            o[0] = f2bf(f0.x); o[1] = f2bf(f0.y); o[2] = f2bf(f0.z); o[3] = f2bf(f0.w);
            o[4] = f2bf(f1.x); o[5] = f2bf(f1.y); o[6] = f2bf(f1.z); o[7] = f2bf(f1.w);
            *(bf16x8*)(dst + base) = o;
        }
        return;
    }
    int p0 = blockIdx.x * 64, c0 = blockIdx.y * 64, b = blockIdx.z;
    #pragma unroll
    for (int i = 0; i < 16; ++i) {
        int idx = i * 256 + t;
        int cl = idx >> 6, pl = idx & 63;
        ts[cl][pl] = x[((size_t)(b * 512 + c0 + cl)) * 1024 + p0 + pl];
    }
    __syncthreads();
    #pragma unroll
    for (int i = 0; i < 16; ++i) {
        int idx = i * 256 + t;
        int pl = idx >> 6, cl = idx & 63;
        xt[((size_t)(b * 1024 + p0 + pl)) * 512 + c0 + cl] = f2bf(ts[cl][pl]);
    }
}

// ---------------------------------------------------------------------------
// 64x128 NT MFMA tile body (K=512): acc[2][4] per thread; 12 KB LDS.
// ---------------------------------------------------------------------------
__device__ inline void nt_tile_64x128(const short* __restrict__ A,
                                      const short* __restrict__ B,
                                      int m0, int n0, int t,
                                      short (*As)[32], short (*Bs)[32],
                                      f32x4 (&acc)[2][4])
{
    int wid = t >> 6, l = t & 63;
    int wm = wid >> 1, wn = wid & 1;
    int srB = t >> 1, halfB = t & 1;
    int swB = (srB >> 1) & 3;
    int sB0 = (halfB * 2) ^ swB, sB1 = (halfB * 2 + 1) ^ swB;
    int srA = t >> 2, qA = t & 3;
    int sA = qA ^ ((srA >> 1) & 3);
    for (int k0 = 0; k0 < 512; k0 += 32) {
        const int4 a0 = *(const int4*)(A + (size_t)(m0 + srA) * 512 + k0 + qA * 8);
        const int4 b0 = *(const int4*)(B + (size_t)(n0 + srB) * 512 + k0 + halfB * 16);
        const int4 b1 = *(const int4*)(B + (size_t)(n0 + srB) * 512 + k0 + halfB * 16 + 8);
        __syncthreads();
        *(int4*)&As[srA][sA * 8] = a0;
        *(int4*)&Bs[srB][sB0 * 8] = b0;
        *(int4*)&Bs[srB][sB1 * 8] = b1;
        __syncthreads();
        bf16x8 af[2], bfr[4];
        #pragma unroll
        for (int mt = 0; mt < 2; ++mt) {
            int r = wm * 32 + mt * 16 + (l & 15);
            af[mt] = *(const bf16x8*)&As[r][(((l >> 4)) ^ ((r >> 1) & 3)) * 8];
        }
        #pragma unroll
        for (int nt = 0; nt < 4; ++nt) {
            int r = wn * 64 + nt * 16 + (l & 15);
            bfr[nt] = *(const bf16x8*)&Bs[r][(((l >> 4)) ^ ((r >> 1) & 3)) * 8];
        }
        #pragma unroll
        for (int mt = 0; mt < 2; ++mt)
            #pragma unroll
            for (int nt = 0; nt < 4; ++nt)
                acc[mt][nt] = __builtin_amdgcn_mfma_f32_16x16x32_bf16(
                    af[mt], bfr[nt], acc[mt][nt], 0, 0, 0);
    }
}

// q projection (dense [m][n] bf16 out); grid (64, 4) = 256 blocks
__global__ __launch_bounds__(256) void gemm_q(
    const short* __restrict__ A, const short* __restrict__ B,
    const float* __restrict__ bias, short* __restrict__ Ob)
{
    __shared__ short As[64][32];
    __shared__ short Bs[128][32];
    int m0 = blockIdx.x * 64, n0 = blockIdx.y * 128;
    int t = threadIdx.x, wid = t >> 6, l = t & 63;
    int wm = wid >> 1, wn = wid & 1;
    f32x4 acc[2][4] = {};
    nt_tile_64x128(A, B, m0, n0, t, As, Bs, acc);
    #pragma unroll
    for (int mt = 0; mt < 2; ++mt)
        #pragma unroll
        for (int nt = 0; nt < 4; ++nt)
            #pragma unroll
            for (int r = 0; r < 4; ++r) {
                int m = m0 + wm * 32 + mt * 16 + (l >> 4) * 4 + r;
                int n = n0 + wn * 64 + nt * 16 + (l & 15);
                Ob[(size_t)m * 512 + n] = f2bf(acc[mt][nt][r] + bias[n]);
            }
}

// k-gemm (bid<256, SWAPPED: D[channel][sample]) + v-gemm (bid>=256, SWAPPED:
// D[sample][channel]); coalesced uint2 fragment-order stores.
__global__ __launch_bounds__(256) void gemm_kv(
    const short* __restrict__ xsb, const short* __restrict__ kwb,
    const float* __restrict__ k_b, short* __restrict__ kfr,
    const short* __restrict__ vwb, const float* __restrict__ v_b,
    short* __restrict__ vfr)
{
    __shared__ short As[64][32];
    __shared__ short Bs[128][32];
    int bid = blockIdx.x;
    int t = threadIdx.x, wid = t >> 6, l = t & 63;
    int wm = wid >> 1, wn = wid & 1;
    f32x4 acc[2][4] = {};
    if (bid < 256) {
        int m0 = (bid >> 5) * 64, n0 = (bid & 31) * 128;
        nt_tile_64x128(kwb, xsb, m0, n0, t, As, Bs, acc);
        int h = m0 >> 6;
        #pragma unroll
        for (int mt = 0; mt < 2; ++mt) {
            int ch0 = m0 + wm * 32 + mt * 16 + (l >> 4) * 4;
            float4 kb4 = *(const float4*)(k_b + ch0);
            int frag = (ch0 >> 5) & 1, gg = (ch0 >> 3) & 3, e = ch0 & 7;
            #pragma unroll
            for (int nt = 0; nt < 4; ++nt) {
                int sm = n0 + wn * 64 + nt * 16 + (l & 15);
                int bq = sm >> 10, p = sm & 1023;
                int T = p >> 4, cs = p & 15;
                uint2 w;
                w.x = (unsigned)(unsigned short)f2bf(acc[mt][nt][0] + kb4.x)
                    | ((unsigned)(unsigned short)f2bf(acc[mt][nt][1] + kb4.y) << 16);
                w.y = (unsigned)(unsigned short)f2bf(acc[mt][nt][2] + kb4.z)
                    | ((unsigned)(unsigned short)f2bf(acc[mt][nt][3] + kb4.w) << 16);
                *(uint2*)(kfr + ((((size_t)(bq * 8 + h) * 64 + T) * 2 + frag) * 64
                                 + gg * 16 + cs) * 8 + e) = w;
            }
        }
    } else {
        int id2 = bid - 256;
        int z = id2 >> 6, rr2 = id2 & 63;
        int m0 = (rr2 >> 2) * 64, n0 = (rr2 & 3) * 128;
        nt_tile_64x128(xsb + (size_t)z * 524288, vwb, m0, n0, t, As, Bs, acc);
        #pragma unroll
        for (int mt = 0; mt < 2; ++mt) {
            int p0 = m0 + wm * 32 + mt * 16 + (l >> 4) * 4;
            int cc = p0 >> 5, gg = (p0 >> 3) & 3, e = p0 & 7;
            #pragma unroll
            for (int nt = 0; nt < 4; ++nt) {
                int ch = n0 + wn * 64 + nt * 16 + (l & 15);
                int h = ch >> 6, wg = (ch & 63) >> 4, cs = ch & 15;
                float vb = v_b[ch];
                h2 plo, phi;
                plo[0] = (_Float16)(acc[mt][nt][0] + vb);
                plo[1] = (_Float16)(acc[mt][nt][1] + vb);
                phi[0] = (_Float16)(acc[mt][nt][2] + vb);
                phi[1] = (_Float16)(acc[mt][nt][3] + vb);
                uint2 w;
                w.x = __builtin_bit_cast(unsigned, plo);
                w.y = __builtin_bit_cast(unsigned, phi);
                *(uint2*)(vfr + ((((size_t)(z * 8 + h) * 4 + wg) * 32 + cc) * 64
                                 + gg * 16 + cs) * 8 + e) = w;
            }
        }
    }
}

// ---------------------------------------------------------------------------
// FUSED offset network + deformable sampling
// ---------------------------------------------------------------------------
__global__ __launch_bounds__(256) void offset_sample(
    const short* __restrict__ qbf, const float* __restrict__ dw_w,
    const float* __restrict__ dw_b, const float* __restrict__ ln_w,
    const float* __restrict__ ln_b, const float* __restrict__ pw_w,
    const short* __restrict__ xt, float* __restrict__ pos,
    short* __restrict__ xs)
{
    __shared__ float red[8];
    __shared__ float2 psh;
    int bid = blockIdx.x;
    int b = bid >> 10, p = bid & 1023;
    int y = p >> 5, x = p & 31;
    int t = threadIdx.x;
    int c0 = 2 * t;
    const short* qb = qbf + (size_t)b * 524288;
    float h0, h1;
    {
        const float* w0 = dw_w + c0 * 9;
        const float* w1 = w0 + 9;
        float s0 = 0.f, s1 = 0.f;
        #pragma unroll
        for (int ky = 0; ky < 3; ++ky) {
            int yy = y + ky - 1;
            if (yy < 0 || yy > 31) continue;
            #pragma unroll
            for (int kx = 0; kx < 3; ++kx) {
                int xx = x + kx - 1;
                if (xx < 0 || xx > 31) continue;
                unsigned u = *(const unsigned*)(qb + (size_t)(yy * 32 + xx) * 512 + c0);
                s0 += bf2f((short)(u & 0xFFFF)) * w0[ky * 3 + kx];
                s1 += bf2f((short)(u >> 16)) * w1[ky * 3 + kx];
            }
        }
        float2 db = *(const float2*)(dw_b + c0);
        h0 = s0 + db.x; h1 = s1 + db.y;
    }
    float ls = h0 + h1;
    float lq = h0 * h0 + h1 * h1;
    #pragma unroll
    for (int s = 32; s >= 1; s >>= 1) {
        ls += __shfl_xor(ls, s);
        lq += __shfl_xor(lq, s);
    }
    int wid = t >> 6, lane = t & 63;
    if (lane == 0) { red[wid] = ls; red[4 + wid] = lq; }
    __syncthreads();
    float mu  = (red[0] + red[1] + red[2] + red[3]) * (1.f / 512.f);
    float var = (red[4] + red[5] + red[6] + red[7]) * (1.f / 512.f) - mu * mu;
    float rstd = rsqrtf(var + 1e-5f);
    float o0, o1;
    {
        float2 lw = *(const float2*)(ln_w + c0);
        float2 lb = *(const float2*)(ln_b + c0);
        float2 p0 = *(const float2*)(pw_w + c0);
        float2 p1 = *(const float2*)(pw_w + 512 + c0);
        float hn0 = (h0 - mu) * rstd * lw.x + lb.x;
        float hn1 = (h1 - mu) * rstd * lw.y + lb.y;
        float g0 = 0.5f * hn0 * (1.f + erff(hn0 * 0.70710678118f));
        float g1 = 0.5f * hn1 * (1.f + erff(hn1 * 0.70710678118f));
        o0 = g0 * p0.x + g1 * p0.y;
        o1 = g0 * p1.x + g1 * p1.y;
    }
    #pragma unroll
    for (int s = 32; s >= 1; s >>= 1) {
        o0 += __shfl_xor(o0, s);
        o1 += __shfl_xor(o1, s);
    }
    __syncthreads();
    if (lane == 0) { red[wid] = o0; red[4 + wid] = o1; }
    __syncthreads();
    if (t == 0) {
        float oy = tanhf(red[0] + red[1] + red[2] + red[3]) * 0.0625f;
        float ox = tanhf(red[4] + red[5] + red[6] + red[7]) * 0.0625f;
        float ry = ((y + 0.5f) * (1.f / 32.f)) * 2.f - 1.f;
        float rx = ((x + 0.5f) * (1.f / 32.f)) * 2.f - 1.f;
        float py = oy + ry, px = ox + rx;
        pos[bid * 2]     = py;
        pos[bid * 2 + 1] = px;
        psh = make_float2(py, px);
    }
    __syncthreads();
    float py = psh.x, px = psh.y;
    float gx = (px + 1.f) * 15.5f;
    float gy = (py + 1.f) * 15.5f;
    float x0f = floorf(gx), y0f = floorf(gy);
    int ix0 = (int)x0f, iy0 = (int)y0f;
    float wx1 = gx - x0f, wx0 = 1.f - wx1;
    float wy1 = gy - y0f, wy0 = 1.f - wy1;
    const short* base = xt + (size_t)b * 524288;
    float a0 = 0.f, a1 = 0.f;
    #pragma unroll
    for (int tap = 0; tap < 4; ++tap) {
        int ix = ix0 + (tap & 1), iy = iy0 + (tap >> 1);
        float w = ((tap & 1) ? wx1 : wx0) * ((tap >> 1) ? wy1 : wy0);
        if (ix >= 0 && ix < 32 && iy >= 0 && iy < 32) {
            unsigned u = *(const unsigned*)(base + (size_t)(iy * 32 + ix) * 512 + c0);
            a0 += bf2f((short)(u & 0xFFFF)) * w;
            a1 += bf2f((short)(u >> 16)) * w;
        }
    }
    unsigned o = ((unsigned)(unsigned short)f2bf(a0)) |
                 (((unsigned)(unsigned short)f2bf(a1)) << 16);
    *(unsigned*)(xs + (size_t)bid * 512 + c0) = o;
}

// ---------------------------------------------------------------------------
// FUSED attention, 512 threads, swapped QK^T, FRAGMENT-ORDERED K/V,
// QUAD RPE table (1 ds_read_b64 per logit).
// NOTE: __launch_bounds__(512) with NO min-wave arg -- earlier rounds' second
// arg capped the register allocator and pushed ep[]/prefetch state to
// scratch (reported VGPR 36-52 << ~100 live values).
// ---------------------------------------------------------------------------
__global__ __launch_bounds__(512) void attn_fused(
    const short* __restrict__ qbf, const short* __restrict__ kfr,
    const short* __restrict__ vfr, const float* __restrict__ pos,
    const uint2* __restrict__ rpet, const float* __restrict__ x,
    const float* __restrict__ gamma, float* __restrict__ attn_out,
    float* __restrict__ out0)
{
    __shared__ __align__(16) char smem_raw[40960];
    uint2*  rpq    = (uint2*)smem_raw;                // [64*64] quad table
    float*  ccsf   = (float*)(smem_raw + 32768);      // [1024*2] (cy,cx) pairs
    short*  Pn     = (short*)smem_raw;                // [16][1032] f16 RAW exp
    float*  S_part = (float*)(smem_raw + 33536);      // [16][8]

    int bid = blockIdx.x;
    int xcd = bid & 7, seq = bid >> 3;
    int m0 = (seq & 63) * 16;
    int bh = xcd + 8 * (seq >> 6);          // h = bh & 7 == xcd
    int b = bh >> 3, h = bh & 7;
    int t = threadIdx.x, wn = t >> 6, l = t & 63;
    int g = l >> 4, c16 = l & 15;

    const uint2* rt = rpet + h * 4096;
    #pragma unroll
    for (int i = 0; i < 8; ++i)
        rpq[i * 512 + t] = rt[i * 512 + t];
    #pragma unroll
    for (int i = 0; i < 2; ++i) {
        int idx = i * 512 + t;
        float2 pf = *(const float2*)(pos + b * 2048 + idx * 2);
        ccsf[idx * 2]     = fmaf(-15.5f, pf.x, 32.f);
        ccsf[idx * 2 + 1] = fmaf(-15.5f, pf.y, 32.f);
    }
    // q fragments (dense layout; only 2 loads/thread)
    int rowm = m0 + c16;
    const short* qrow = qbf + ((size_t)(b * 1024 + rowm) * 512 + h * 64 + g * 8);
    bf16x8 aq0 = *(const bf16x8*)qrow;
    bf16x8 aq1 = *(const bf16x8*)(qrow + 32);
    float qy = (((rowm >> 5) + 0.5f) * (1.f / 16.f) - 1.f) * 15.5f;
    float qx = (((rowm & 31) + 0.5f) * (1.f / 16.f) - 1.f) * 15.5f;
    __syncthreads();

    // ---- pass A: 8 n-tiles; K frags coalesced + 2-deep register prefetch
    float Ssum = 0.f;
    float e0, e1;
    unsigned ep[16];
    const short* kr = kfr + (size_t)(bh * 64 + wn * 8) * 1024 + l * 8;
    bf16x8 ka0 = *(const bf16x8*)kr;
    bf16x8 kb0 = *(const bf16x8*)(kr + 512);
    bf16x8 ka1 = *(const bf16x8*)(kr + 1024);
    bf16x8 kb1 = *(const bf16x8*)(kr + 1536);
    #pragma unroll
    for (int nt = 0; nt < 8; ++nt) {
        bf16x8 bk0 = ka0, bk1 = kb0;
        ka0 = ka1; kb0 = kb1;
        if (nt < 6) {
            ka1 = *(const bf16x8*)(kr + (nt + 2) * 1024);
            kb1 = *(const bf16x8*)(kr + (nt + 2) * 1024 + 512);
        }
        __builtin_amdgcn_s_setprio(1);
        f32x4 acc = {0.f, 0.f, 0.f, 0.f};
        acc = __builtin_amdgcn_mfma_f32_16x16x32_bf16(bk0, aq0, acc, 0, 0, 0);
        acc = __builtin_amdgcn_mfma_f32_16x16x32_bf16(bk1, aq1, acc, 0, 0, 0);
        __builtin_amdgcn_s_setprio(0);
        int nb = wn * 128 + nt * 16;
        const float* cbase = ccsf + (nb + g * 4) * 2;
        float4 c01 = *(const float4*)cbase;        // (cy,cx) for r=0,1
        float4 c23 = *(const float4*)(cbase + 4);  // (cy,cx) for r=2,3
        #pragma unroll
        for (int r = 0; r < 4; ++r) {
            float cy = (r == 0) ? c01.x : (r == 1) ? c01.z : (r == 2) ? c23.x : c23.z;
            float cx = (r == 0) ? c01.y : (r == 1) ? c01.w : (r == 2) ? c23.y : c23.w;
            float gyp = qy + cy;
            float gxp = qx + cx;
            float fy = floorf(gyp), fx = floorf(gxp);
            float wy1 = gyp - fy, wx1 = gxp - fx;
            int ad = (int)(fy * 64.f + fx);
            uint2 q4 = rpq[ad];                      // all 4 taps, one b64
            h2 lo = __builtin_bit_cast(h2, q4.x);
            h2 hi = __builtin_bit_cast(h2, q4.y);
            h2 wp = pkrtz(1.f - wx1, wx1);
            float t0 = dot2(lo, wp);
            float t1 = dot2(hi, wp);
            float bias2 = t0 + wy1 * (t1 - t0);      // already x log2e
            float logit2 = fmaf(acc[r], 0.1803368801f, bias2);  // 0.125*log2e
            float e = fast_exp2(logit2);
            Ssum += e;
            if (r == 0) e0 = e;
            else if (r == 1) ep[nt * 2] = __builtin_bit_cast(unsigned, pkrtz(e0, e));
            else if (r == 2) e1 = e;
            else ep[nt * 2 + 1] = __builtin_bit_cast(unsigned, pkrtz(e1, e));
        }
    }
    Ssum += __shfl_xor(Ssum, 16);
    Ssum += __shfl_xor(Ssum, 32);
    __syncthreads();   // ALL pass-A LDS reads retired; quad/ccs region dead
    if (l < 16) S_part[c16 * 8 + wn] = Ssum;
    // ---- raw exp pairs -> Pn[m=c16][n]
    short* prow = Pn + c16 * 1032 + wn * 128;
    #pragma unroll
    for (int nt = 0; nt < 8; ++nt) {
        uint2 w;
        w.x = ep[nt * 2];
        w.y = ep[nt * 2 + 1];
        *(uint2*)(prow + nt * 16 + g * 4) = w;
    }
    __syncthreads();
    float4 sa = *(const float4*)&S_part[c16 * 8];
    float4 sb = *(const float4*)&S_part[c16 * 8 + 4];
    float invS = 1.f / (sa.x + sa.y + sa.z + sa.w + sb.x + sb.y + sb.z + sb.w);

    size_t obase = ((size_t)(bh * 1024 + m0)) * 1024;
    if (wn >= 4) {
        // ---- attn fp32 stream: waves 4-7, nontemporal float4 stores
        int tw = t - 256;
        #pragma unroll
        for (int row = 0; row < 16; ++row) {
            float ivr = __shfl(invS, row);
            uint2 pr8 = *(const uint2*)(Pn + row * 1032 + tw * 4);
            h2 a = __builtin_bit_cast(h2, pr8.x);
            h2 bb = __builtin_bit_cast(h2, pr8.y);
            float4 vv = make_float4((float)a[0] * ivr, (float)a[1] * ivr,
                                    (float)bb[0] * ivr, (float)bb[1] * ivr);
            nt_store4(vv, attn_out + obase + (size_t)row * 1024 + tw * 4);
        }
    } else {
        // ---- PV: wave wn owns channels wn*16..+15; V fragment-ordered
        const short* Vb = vfr + (size_t)((bh * 4 + wn) * 32) * 512;
        const short* Prow = Pn + c16 * 1032 + g * 8;
        f32x4 dacc = {0.f, 0.f, 0.f, 0.f};
        __builtin_amdgcn_s_setprio(1);
        #pragma unroll
        for (int cc = 0; cc < 32; ++cc) {
            f16x8 pa  = *(const f16x8*)(Prow + cc * 32);
            f16x8 vb8 = *(const f16x8*)(Vb + cc * 512 + l * 8);
            dacc = __builtin_amdgcn_mfma_f32_16x16x32_f16(pa, vb8, dacc, 0, 0, 0);
        }
        __builtin_amdgcn_s_setprio(0);
        float gm = gamma[0];
        float gi0 = gm * __shfl(invS, g * 4);
        float gi1 = gm * __shfl(invS, g * 4 + 1);
        float gi2 = gm * __shfl(invS, g * 4 + 2);
        float gi3 = gm * __shfl(invS, g * 4 + 3);
        int ch = h * 64 + wn * 16 + c16;
        int m = m0 + g * 4;
        size_t idx = ((size_t)(b * 512 + ch)) * 1024 + m;
        float4 xv = *(const float4*)(x + idx);
        float4 ov;
        ov.x = gi0 * dacc[0] + xv.x;
        ov.y = gi1 * dacc[1] + xv.y;
        ov.z = gi2 * dacc[2] + xv.z;
        ov.w = gi3 * dacc[3] + xv.w;
        nt_store4(ov, out0 + idx);
    }
}

extern "C" void kernel_launch(void* const* d_in, const int* in_sizes, int n_in,
                              void* d_out, int out_size, void* d_ws, size_t ws_size,
                              hipStream_t stream) {
    const float* x     = (const float*)d_in[0];
    const float* dw_w  = (const float*)d_in[1];
    const float* dw_b  = (const float*)d_in[2];
    const float* ln_w  = (const float*)d_in[3];
    const float* ln_b  = (const float*)d_in[4];
    const float* pw_w  = (const float*)d_in[5];
    const float* q_w   = (const float*)d_in[6];
    const float* q_b   = (const float*)d_in[7];
    const float* k_w   = (const float*)d_in[8];
    const float* k_b   = (const float*)d_in[9];
    const float* v_w   = (const float*)d_in[10];
    const float* v_b   = (const float*)d_in[11];
    const float* rpe   = (const float*)d_in[12];
    const float* gamma = (const float*)d_in[13];

    float* out0 = (float*)d_out;
    float* attn = out0 + (size_t)4 * 512 * 1024;

    char* w = (char*)d_ws;
    short*    xt   = (short*)w;                    // 4 MB
    short*    qwb  = (short*)(w + 4194304);
    short*    kwb  = (short*)(w + 4718592);
    short*    vwb  = (short*)(w + 5242880);
    short*    qbf  = (short*)(w + 5767168);        // 4 MB dense q
    short*    xsb  = (short*)(w + 9961472);        // 4 MB
    short*    kfr  = (short*)(w + 14155776);       // 4 MB frag-ordered K
    short*    vfr  = (short*)(w + 18350080);       // 4 MB frag-ordered V (f16)
    float*    pos  = (float*)(w + 22544384);       // 32 KB
    uint2*    rpet = (uint2*)(w + 22577152);       // 8*4096*8 = 256 KB quad table

    prep_x<<<dim3(16, 8, 6), 256, 0, stream>>>(x, xt, q_w, k_w, v_w, qwb, kwb,
                                               vwb, rpe, rpet);
    gemm_q<<<dim3(64, 4), 256, 0, stream>>>(xt, qwb, q_b, qbf);
    offset_sample<<<4096, 256, 0, stream>>>(qbf, dw_w, dw_b, ln_w, ln_b, pw_w,
                                            xt, pos, xsb);
    gemm_kv<<<512, 256, 0, stream>>>(xsb, kwb, k_b, kfr, vwb, v_b, vfr);
    attn_fused<<<2048, 512, 0, stream>>>(qbf, kfr, vfr, pos, rpet, x,
                                         gamma, attn, out0);
}

// Round 17
// 107.533 us; speedup vs baseline: 1.0417x; 1.0417x over previous
//
#include <hip/hip_runtime.h>
#include <hip/hip_bf16.h>
#include <math.h>

typedef short bf16x8 __attribute__((ext_vector_type(8)));
typedef _Float16 f16x8 __attribute__((ext_vector_type(8)));
typedef float f32x4 __attribute__((ext_vector_type(4)));
typedef _Float16 h2 __attribute__((ext_vector_type(2)));

__device__ inline short f2bf(float f) {
    union { float f; unsigned u; } v; v.f = f;
    unsigned r = v.u + 0x7FFFu + ((v.u >> 16) & 1u);
    return (short)(r >> 16);
}
__device__ inline float bf2f(short s) {
    union { unsigned u; float f; } v; v.u = ((unsigned)(unsigned short)s) << 16;
    return v.f;
}
__device__ inline h2 pkrtz(float a, float b) {
    return __builtin_bit_cast(h2, __builtin_amdgcn_cvt_pkrtz(a, b));
}
__device__ inline float fast_exp2(float x) {
    float r;
    asm("v_exp_f32 %0, %1" : "=v"(r) : "v"(x));
    return r;
}
__device__ inline float dot2(h2 a, h2 b) {
#if __has_builtin(__builtin_amdgcn_fdot2)
    return __builtin_amdgcn_fdot2(a, b, 0.f, false);
#else
    return (float)a[0] * (float)b[0] + (float)a[1] * (float)b[1];
#endif
}
__device__ inline void nt_store4(float4 v, float* p) {
    __builtin_nontemporal_store(__builtin_bit_cast(f32x4, v), (f32x4*)p);
}

// ---------------------------------------------------------------------------
// z<4: transpose-cast x -> xt [b][p][c] bf16.  z==4: weight cast.
// z==5 (x<8,y==0): per-head 64x64 QUAD RPE table (4 bilinear taps packed as
// 4xf16 in 8B, pre-scaled by log2e).
// ---------------------------------------------------------------------------
__global__ __launch_bounds__(256) void prep_x(
    const float* __restrict__ x, short* __restrict__ xt,
    const float* __restrict__ qw, const float* __restrict__ kw,
    const float* __restrict__ vw, short* __restrict__ qwb,
    short* __restrict__ kwb, short* __restrict__ vwb,
    const float* __restrict__ rpe, uint2* __restrict__ rpet)
{
    __shared__ float ts[64][65];
    int t = threadIdx.x;
    if (blockIdx.z == 5) {   // quad RPE plane: head = blockIdx.x
        if (blockIdx.y != 0 || blockIdx.x >= 8) return;
        int hh = blockIdx.x;
        const float* rh = rpe + hh * 3969;
        const float L2E = 1.44269504f;
        auto P = [&](int y, int xx) -> float {
            return (y >= 1 && y <= 63 && xx >= 1 && xx <= 63)
                 ? rh[(y - 1) * 63 + (xx - 1)] * L2E : 0.f;
        };
        #pragma unroll
        for (int i = 0; i < 16; ++i) {
            int j = i * 256 + t;          // j < 4096
            int qy = j >> 6, qx = j & 63;
            h2 lo, hi;
            lo[0] = (_Float16)P(qy, qx);     lo[1] = (_Float16)P(qy, qx + 1);
            hi[0] = (_Float16)P(qy + 1, qx); hi[1] = (_Float16)P(qy + 1, qx + 1);
            uint2 w;
            w.x = __builtin_bit_cast(unsigned, lo);
            w.y = __builtin_bit_cast(unsigned, hi);
            rpet[hh * 4096 + j] = w;
        }
        return;
    }
    if (blockIdx.z == 4) {   // weight cast plane
        int f = blockIdx.y * 16 + blockIdx.x;
        int base = (f * 256 + t) * 8;
        #pragma unroll
        for (int w = 0; w < 3; ++w) {
            const float* src = (w == 0) ? qw : (w == 1) ? kw : vw;
            short* dst = (w == 0) ? qwb : (w == 1) ? kwb : vwb;
            float4 f0 = *(const float4*)(src + base);
            float4 f1 = *(const float4*)(src + base + 4);
            bf16x8 o;
            o[0] = f2bf(f0.x); o[1] = f2bf(f0.y); o[2] = f2bf(f0.z); o[3] = f2bf(f0.w);
            o[4] = f2bf(f1.x); o[5] = f2bf(f1.y); o[6] = f2bf(f1.z); o[7] = f2bf(f1.w);
            *(bf16x8*)(dst + base) = o;
        }
        return;
    }
    int p0 = blockIdx.x * 64, c0 = blockIdx.y * 64, b = blockIdx.z;
    #pragma unroll
    for (int i = 0; i < 16; ++i) {
        int idx = i * 256 + t;
        int cl = idx >> 6, pl = idx & 63;
        ts[cl][pl] = x[((size_t)(b * 512 + c0 + cl)) * 1024 + p0 + pl];
    }
    __syncthreads();
    #pragma unroll
    for (int i = 0; i < 16; ++i) {
        int idx = i * 256 + t;
        int pl = idx >> 6, cl = idx & 63;
        xt[((size_t)(b * 1024 + p0 + pl)) * 512 + c0 + cl] = f2bf(ts[cl][pl]);
    }
}

// ---------------------------------------------------------------------------
// 64x128 NT MFMA tile body (K=512): acc[2][4] per thread; 12 KB LDS.
// ---------------------------------------------------------------------------
__device__ inline void nt_tile_64x128(const short* __restrict__ A,
                                      const short* __restrict__ B,
                                      int m0, int n0, int t,
                                      short (*As)[32], short (*Bs)[32],
                                      f32x4 (&acc)[2][4])
{
    int wid = t >> 6, l = t & 63;
    int wm = wid >> 1, wn = wid & 1;
    int srB = t >> 1, halfB = t & 1;
    int swB = (srB >> 1) & 3;
    int sB0 = (halfB * 2) ^ swB, sB1 = (halfB * 2 + 1) ^ swB;
    int srA = t >> 2, qA = t & 3;
    int sA = qA ^ ((srA >> 1) & 3);
    for (int k0 = 0; k0 < 512; k0 += 32) {
        const int4 a0 = *(const int4*)(A + (size_t)(m0 + srA) * 512 + k0 + qA * 8);
        const int4 b0 = *(const int4*)(B + (size_t)(n0 + srB) * 512 + k0 + halfB * 16);
        const int4 b1 = *(const int4*)(B + (size_t)(n0 + srB) * 512 + k0 + halfB * 16 + 8);
        __syncthreads();
        *(int4*)&As[srA][sA * 8] = a0;
        *(int4*)&Bs[srB][sB0 * 8] = b0;
        *(int4*)&Bs[srB][sB1 * 8] = b1;
        __syncthreads();
        bf16x8 af[2], bfr[4];
        #pragma unroll
        for (int mt = 0; mt < 2; ++mt) {
            int r = wm * 32 + mt * 16 + (l & 15);
            af[mt] = *(const bf16x8*)&As[r][(((l >> 4)) ^ ((r >> 1) & 3)) * 8];
        }
        #pragma unroll
        for (int nt = 0; nt < 4; ++nt) {
            int r = wn * 64 + nt * 16 + (l & 15);
            bfr[nt] = *(const bf16x8*)&Bs[r][(((l >> 4)) ^ ((r >> 1) & 3)) * 8];
        }
        #pragma unroll
        for (int mt = 0; mt < 2; ++mt)
            #pragma unroll
            for (int nt = 0; nt < 4; ++nt)
                acc[mt][nt] = __builtin_amdgcn_mfma_f32_16x16x32_bf16(
                    af[mt], bfr[nt], acc[mt][nt], 0, 0, 0);
    }
}

// q projection (dense [m][n] bf16 out); grid (64, 4) = 256 blocks
__global__ __launch_bounds__(256) void gemm_q(
    const short* __restrict__ A, const short* __restrict__ B,
    const float* __restrict__ bias, short* __restrict__ Ob)
{
    __shared__ short As[64][32];
    __shared__ short Bs[128][32];
    int m0 = blockIdx.x * 64, n0 = blockIdx.y * 128;
    int t = threadIdx.x, wid = t >> 6, l = t & 63;
    int wm = wid >> 1, wn = wid & 1;
    f32x4 acc[2][4] = {};
    nt_tile_64x128(A, B, m0, n0, t, As, Bs, acc);
    #pragma unroll
    for (int mt = 0; mt < 2; ++mt)
        #pragma unroll
        for (int nt = 0; nt < 4; ++nt)
            #pragma unroll
            for (int r = 0; r < 4; ++r) {
                int m = m0 + wm * 32 + mt * 16 + (l >> 4) * 4 + r;
                int n = n0 + wn * 64 + nt * 16 + (l & 15);
                Ob[(size_t)m * 512 + n] = f2bf(acc[mt][nt][r] + bias[n]);
            }
}

// k-gemm (bid<256, SWAPPED: D[channel][sample]) + v-gemm (bid>=256, SWAPPED:
// D[sample][channel]); coalesced uint2 fragment-order stores.
__global__ __launch_bounds__(256) void gemm_kv(
    const short* __restrict__ xsb, const short* __restrict__ kwb,
    const float* __restrict__ k_b, short* __restrict__ kfr,
    const short* __restrict__ vwb, const float* __restrict__ v_b,
    short* __restrict__ vfr)
{
    __shared__ short As[64][32];
    __shared__ short Bs[128][32];
    int bid = blockIdx.x;
    int t = threadIdx.x, wid = t >> 6, l = t & 63;
    int wm = wid >> 1, wn = wid & 1;
    f32x4 acc[2][4] = {};
    if (bid < 256) {
        int m0 = (bid >> 5) * 64, n0 = (bid & 31) * 128;
        nt_tile_64x128(kwb, xsb, m0, n0, t, As, Bs, acc);
        int h = m0 >> 6;
        #pragma unroll
        for (int mt = 0; mt < 2; ++mt) {
            int ch0 = m0 + wm * 32 + mt * 16 + (l >> 4) * 4;
            float4 kb4 = *(const float4*)(k_b + ch0);
            int frag = (ch0 >> 5) & 1, gg = (ch0 >> 3) & 3, e = ch0 & 7;
            #pragma unroll
            for (int nt = 0; nt < 4; ++nt) {
                int sm = n0 + wn * 64 + nt * 16 + (l & 15);
                int bq = sm >> 10, p = sm & 1023;
                int T = p >> 4, cs = p & 15;
                uint2 w;
                w.x = (unsigned)(unsigned short)f2bf(acc[mt][nt][0] + kb4.x)
                    | ((unsigned)(unsigned short)f2bf(acc[mt][nt][1] + kb4.y) << 16);
                w.y = (unsigned)(unsigned short)f2bf(acc[mt][nt][2] + kb4.z)
                    | ((unsigned)(unsigned short)f2bf(acc[mt][nt][3] + kb4.w) << 16);
                *(uint2*)(kfr + ((((size_t)(bq * 8 + h) * 64 + T) * 2 + frag) * 64
                                 + gg * 16 + cs) * 8 + e) = w;
            }
        }
    } else {
        int id2 = bid - 256;
        int z = id2 >> 6, rr2 = id2 & 63;
        int m0 = (rr2 >> 2) * 64, n0 = (rr2 & 3) * 128;
        nt_tile_64x128(xsb + (size_t)z * 524288, vwb, m0, n0, t, As, Bs, acc);
        #pragma unroll
        for (int mt = 0; mt < 2; ++mt) {
            int p0 = m0 + wm * 32 + mt * 16 + (l >> 4) * 4;
            int cc = p0 >> 5, gg = (p0 >> 3) & 3, e = p0 & 7;
            #pragma unroll
            for (int nt = 0; nt < 4; ++nt) {
                int ch = n0 + wn * 64 + nt * 16 + (l & 15);
                int h = ch >> 6, wg = (ch & 63) >> 4, cs = ch & 15;
                float vb = v_b[ch];
                h2 plo, phi;
                plo[0] = (_Float16)(acc[mt][nt][0] + vb);
                plo[1] = (_Float16)(acc[mt][nt][1] + vb);
                phi[0] = (_Float16)(acc[mt][nt][2] + vb);
                phi[1] = (_Float16)(acc[mt][nt][3] + vb);
                uint2 w;
                w.x = __builtin_bit_cast(unsigned, plo);
                w.y = __builtin_bit_cast(unsigned, phi);
                *(uint2*)(vfr + ((((size_t)(z * 8 + h) * 4 + wg) * 32 + cc) * 64
                                 + gg * 16 + cs) * 8 + e) = w;
            }
        }
    }
}

// ---------------------------------------------------------------------------
// FUSED offset network + deformable sampling
// ---------------------------------------------------------------------------
__global__ __launch_bounds__(256) void offset_sample(
    const short* __restrict__ qbf, const float* __restrict__ dw_w,
    const float* __restrict__ dw_b, const float* __restrict__ ln_w,
    const float* __restrict__ ln_b, const float* __restrict__ pw_w,
    const short* __restrict__ xt, float* __restrict__ pos,
    short* __restrict__ xs)
{
    __shared__ float red[8];
    __shared__ float2 psh;
    int bid = blockIdx.x;
    int b = bid >> 10, p = bid & 1023;
    int y = p >> 5, x = p & 31;
    int t = threadIdx.x;
    int c0 = 2 * t;
    const short* qb = qbf + (size_t)b * 524288;
    float h0, h1;
    {
        const float* w0 = dw_w + c0 * 9;
        const float* w1 = w0 + 9;
        float s0 = 0.f, s1 = 0.f;
        #pragma unroll
        for (int ky = 0; ky < 3; ++ky) {
            int yy = y + ky - 1;
            if (yy < 0 || yy > 31) continue;
            #pragma unroll
            for (int kx = 0; kx < 3; ++kx) {
                int xx = x + kx - 1;
                if (xx < 0 || xx > 31) continue;
                unsigned u = *(const unsigned*)(qb + (size_t)(yy * 32 + xx) * 512 + c0);
                s0 += bf2f((short)(u & 0xFFFF)) * w0[ky * 3 + kx];
                s1 += bf2f((short)(u >> 16)) * w1[ky * 3 + kx];
            }
        }
        float2 db = *(const float2*)(dw_b + c0);
        h0 = s0 + db.x; h1 = s1 + db.y;
    }
    float ls = h0 + h1;
    float lq = h0 * h0 + h1 * h1;
    #pragma unroll
    for (int s = 32; s >= 1; s >>= 1) {
        ls += __shfl_xor(ls, s);
        lq += __shfl_xor(lq, s);
    }
    int wid = t >> 6, lane = t & 63;
    if (lane == 0) { red[wid] = ls; red[4 + wid] = lq; }
    __syncthreads();
    float mu  = (red[0] + red[1] + red[2] + red[3]) * (1.f / 512.f);
    float var = (red[4] + red[5] + red[6] + red[7]) * (1.f / 512.f) - mu * mu;
    float rstd = rsqrtf(var + 1e-5f);
    float o0, o1;
    {
        float2 lw = *(const float2*)(ln_w + c0);
        float2 lb = *(const float2*)(ln_b + c0);
        float2 p0 = *(const float2*)(pw_w + c0);
        float2 p1 = *(const float2*)(pw_w + 512 + c0);
        float hn0 = (h0 - mu) * rstd * lw.x + lb.x;
        float hn1 = (h1 - mu) * rstd * lw.y + lb.y;
        float g0 = 0.5f * hn0 * (1.f + erff(hn0 * 0.70710678118f));
        float g1 = 0.5f * hn1 * (1.f + erff(hn1 * 0.70710678118f));
        o0 = g0 * p0.x + g1 * p0.y;
        o1 = g0 * p1.x + g1 * p1.y;
    }
    #pragma unroll
    for (int s = 32; s >= 1; s >>= 1) {
        o0 += __shfl_xor(o0, s);
        o1 += __shfl_xor(o1, s);
    }
    __syncthreads();
    if (lane == 0) { red[wid] = o0; red[4 + wid] = o1; }
    __syncthreads();
    if (t == 0) {
        float oy = tanhf(red[0] + red[1] + red[2] + red[3]) * 0.0625f;
        float ox = tanhf(red[4] + red[5] + red[6] + red[7]) * 0.0625f;
        float ry = ((y + 0.5f) * (1.f / 32.f)) * 2.f - 1.f;
        float rx = ((x + 0.5f) * (1.f / 32.f)) * 2.f - 1.f;
        float py = oy + ry, px = ox + rx;
        pos[bid * 2]     = py;
        pos[bid * 2 + 1] = px;
        psh = make_float2(py, px);
    }
    __syncthreads();
    float py = psh.x, px = psh.y;
    float gx = (px + 1.f) * 15.5f;
    float gy = (py + 1.f) * 15.5f;
    float x0f = floorf(gx), y0f = floorf(gy);
    int ix0 = (int)x0f, iy0 = (int)y0f;
    float wx1 = gx - x0f, wx0 = 1.f - wx1;
    float wy1 = gy - y0f, wy0 = 1.f - wy1;
    const short* base = xt + (size_t)b * 524288;
    float a0 = 0.f, a1 = 0.f;
    #pragma unroll
    for (int tap = 0; tap < 4; ++tap) {
        int ix = ix0 + (tap & 1), iy = iy0 + (tap >> 1);
        float w = ((tap & 1) ? wx1 : wx0) * ((tap >> 1) ? wy1 : wy0);
        if (ix >= 0 && ix < 32 && iy >= 0 && iy < 32) {
            unsigned u = *(const unsigned*)(base + (size_t)(iy * 32 + ix) * 512 + c0);
            a0 += bf2f((short)(u & 0xFFFF)) * w;
            a1 += bf2f((short)(u >> 16)) * w;
        }
    }
    unsigned o = ((unsigned)(unsigned short)f2bf(a0)) |
                 (((unsigned)(unsigned short)f2bf(a1)) << 16);
    *(unsigned*)(xs + (size_t)bid * 512 + c0) = o;
}

// ---------------------------------------------------------------------------
// FUSED attention, 512 threads, swapped QK^T, FRAGMENT-ORDERED K/V,
// QUAD RPE table (1 ds_read_b64 per logit). launch_bounds(512,4) = best-known.
// Stream phase: ALL 8 waves write attn (2 rows each, coalesced NT float4);
// waves 0-3 then run PV (both phases only read Pn -> no extra barrier).
// ---------------------------------------------------------------------------
__global__ __launch_bounds__(512, 4) void attn_fused(
    const short* __restrict__ qbf, const short* __restrict__ kfr,
    const short* __restrict__ vfr, const float* __restrict__ pos,
    const uint2* __restrict__ rpet, const float* __restrict__ x,
    const float* __restrict__ gamma, float* __restrict__ attn_out,
    float* __restrict__ out0)
{
    __shared__ __align__(16) char smem_raw[40960];
    uint2*  rpq    = (uint2*)smem_raw;                // [64*64] quad table
    float*  ccsf   = (float*)(smem_raw + 32768);      // [1024*2] (cy,cx) pairs
    short*  Pn     = (short*)smem_raw;                // [16][1032] f16 RAW exp
    float*  S_part = (float*)(smem_raw + 33536);      // [16][8]

    int bid = blockIdx.x;
    int xcd = bid & 7, seq = bid >> 3;
    int m0 = (seq & 63) * 16;
    int bh = xcd + 8 * (seq >> 6);          // h = bh & 7 == xcd
    int b = bh >> 3, h = bh & 7;
    int t = threadIdx.x, wn = t >> 6, l = t & 63;
    int g = l >> 4, c16 = l & 15;

    const uint2* rt = rpet + h * 4096;
    #pragma unroll
    for (int i = 0; i < 8; ++i)
        rpq[i * 512 + t] = rt[i * 512 + t];
    #pragma unroll
    for (int i = 0; i < 2; ++i) {
        int idx = i * 512 + t;
        float2 pf = *(const float2*)(pos + b * 2048 + idx * 2);
        ccsf[idx * 2]     = fmaf(-15.5f, pf.x, 32.f);
        ccsf[idx * 2 + 1] = fmaf(-15.5f, pf.y, 32.f);
    }
    // q fragments (dense layout; only 2 loads/thread)
    int rowm = m0 + c16;
    const short* qrow = qbf + ((size_t)(b * 1024 + rowm) * 512 + h * 64 + g * 8);
    bf16x8 aq0 = *(const bf16x8*)qrow;
    bf16x8 aq1 = *(const bf16x8*)(qrow + 32);
    float qy = (((rowm >> 5) + 0.5f) * (1.f / 16.f) - 1.f) * 15.5f;
    float qx = (((rowm & 31) + 0.5f) * (1.f / 16.f) - 1.f) * 15.5f;
    __syncthreads();

    // ---- pass A: 8 n-tiles; K frags coalesced + 2-deep register prefetch
    float Ssum = 0.f;
    float e0, e1;
    unsigned ep[16];
    const short* kr = kfr + (size_t)(bh * 64 + wn * 8) * 1024 + l * 8;
    bf16x8 ka0 = *(const bf16x8*)kr;
    bf16x8 kb0 = *(const bf16x8*)(kr + 512);
    bf16x8 ka1 = *(const bf16x8*)(kr + 1024);
    bf16x8 kb1 = *(const bf16x8*)(kr + 1536);
    #pragma unroll
    for (int nt = 0; nt < 8; ++nt) {
        bf16x8 bk0 = ka0, bk1 = kb0;
        ka0 = ka1; kb0 = kb1;
        if (nt < 6) {
            ka1 = *(const bf16x8*)(kr + (nt + 2) * 1024);
            kb1 = *(const bf16x8*)(kr + (nt + 2) * 1024 + 512);
        }
        __builtin_amdgcn_s_setprio(1);
        f32x4 acc = {0.f, 0.f, 0.f, 0.f};
        acc = __builtin_amdgcn_mfma_f32_16x16x32_bf16(bk0, aq0, acc, 0, 0, 0);
        acc = __builtin_amdgcn_mfma_f32_16x16x32_bf16(bk1, aq1, acc, 0, 0, 0);
        __builtin_amdgcn_s_setprio(0);
        int nb = wn * 128 + nt * 16;
        const float* cbase = ccsf + (nb + g * 4) * 2;
        float4 c01 = *(const float4*)cbase;        // (cy,cx) for r=0,1
        float4 c23 = *(const float4*)(cbase + 4);  // (cy,cx) for r=2,3
        #pragma unroll
        for (int r = 0; r < 4; ++r) {
            float cy = (r == 0) ? c01.x : (r == 1) ? c01.z : (r == 2) ? c23.x : c23.z;
            float cx = (r == 0) ? c01.y : (r == 1) ? c01.w : (r == 2) ? c23.y : c23.w;
            float gyp = qy + cy;
            float gxp = qx + cx;
            float fy = floorf(gyp), fx = floorf(gxp);
            float wy1 = gyp - fy, wx1 = gxp - fx;
            int ad = (int)(fy * 64.f + fx);
            uint2 q4 = rpq[ad];                      // all 4 taps, one b64
            h2 lo = __builtin_bit_cast(h2, q4.x);
            h2 hi = __builtin_bit_cast(h2, q4.y);
            h2 wp = pkrtz(1.f - wx1, wx1);
            float t0 = dot2(lo, wp);
            float t1 = dot2(hi, wp);
            float bias2 = t0 + wy1 * (t1 - t0);      // already x log2e
            float logit2 = fmaf(acc[r], 0.1803368801f, bias2);  // 0.125*log2e
            float e = fast_exp2(logit2);
            Ssum += e;
            if (r == 0) e0 = e;
            else if (r == 1) ep[nt * 2] = __builtin_bit_cast(unsigned, pkrtz(e0, e));
            else if (r == 2) e1 = e;
            else ep[nt * 2 + 1] = __builtin_bit_cast(unsigned, pkrtz(e1, e));
        }
    }
    Ssum += __shfl_xor(Ssum, 16);
    Ssum += __shfl_xor(Ssum, 32);
    __syncthreads();   // ALL pass-A LDS reads retired; quad/ccs region dead
    if (l < 16) S_part[c16 * 8 + wn] = Ssum;
    // ---- raw exp pairs -> Pn[m=c16][n]
    short* prow = Pn + c16 * 1032 + wn * 128;
    #pragma unroll
    for (int nt = 0; nt < 8; ++nt) {
        uint2 w;
        w.x = ep[nt * 2];
        w.y = ep[nt * 2 + 1];
        *(uint2*)(prow + nt * 16 + g * 4) = w;
    }
    __syncthreads();
    float4 sa = *(const float4*)&S_part[c16 * 8];
    float4 sb = *(const float4*)&S_part[c16 * 8 + 4];
    float invS = 1.f / (sa.x + sa.y + sa.z + sa.w + sb.x + sb.y + sb.z + sb.w);

    size_t obase = ((size_t)(bh * 1024 + m0)) * 1024;
    // ---- stream: ALL 8 waves; wave wn owns rows 2wn, 2wn+1 (4 x 256-col
    //      quarters each, coalesced NT float4)
    #pragma unroll
    for (int rr = 0; rr < 2; ++rr) {
        int row = wn * 2 + rr;
        float ivr = __shfl(invS, row);
        #pragma unroll
        for (int qq = 0; qq < 4; ++qq) {
            int col = qq * 256 + l * 4;
            uint2 pr8 = *(const uint2*)(Pn + row * 1032 + col);
            h2 a = __builtin_bit_cast(h2, pr8.x);
            h2 bb = __builtin_bit_cast(h2, pr8.y);
            float4 vv = make_float4((float)a[0] * ivr, (float)a[1] * ivr,
                                    (float)bb[0] * ivr, (float)bb[1] * ivr);
            nt_store4(vv, attn_out + obase + (size_t)row * 1024 + col);
        }
    }
    if (wn < 4) {
        // ---- PV: wave wn owns channels wn*16..+15; V fragment-ordered
        const short* Vb = vfr + (size_t)((bh * 4 + wn) * 32) * 512;
        const short* Prow = Pn + c16 * 1032 + g * 8;
        f32x4 dacc = {0.f, 0.f, 0.f, 0.f};
        __builtin_amdgcn_s_setprio(1);
        #pragma unroll
        for (int cc = 0; cc < 32; ++cc) {
            f16x8 pa  = *(const f16x8*)(Prow + cc * 32);
            f16x8 vb8 = *(const f16x8*)(Vb + cc * 512 + l * 8);
            dacc = __builtin_amdgcn_mfma_f32_16x16x32_f16(pa, vb8, dacc, 0, 0, 0);
        }
        __builtin_amdgcn_s_setprio(0);
        float gm = gamma[0];
        float gi0 = gm * __shfl(invS, g * 4);
        float gi1 = gm * __shfl(invS, g * 4 + 1);
        float gi2 = gm * __shfl(invS, g * 4 + 2);
        float gi3 = gm * __shfl(invS, g * 4 + 3);
        int ch = h * 64 + wn * 16 + c16;
        int m = m0 + g * 4;
        size_t idx = ((size_t)(b * 512 + ch)) * 1024 + m;
        float4 xv = *(const float4*)(x + idx);
        float4 ov;
        ov.x = gi0 * dacc[0] + xv.x;
        ov.y = gi1 * dacc[1] + xv.y;
        ov.z = gi2 * dacc[2] + xv.z;
        ov.w = gi3 * dacc[3] + xv.w;
        nt_store4(ov, out0 + idx);
    }
}

extern "C" void kernel_launch(void* const* d_in, const int* in_sizes, int n_in,
                              void* d_out, int out_size, void* d_ws, size_t ws_size,
                              hipStream_t stream) {
    const float* x     = (const float*)d_in[0];
    const float* dw_w  = (const float*)d_in[1];
    const float* dw_b  = (const float*)d_in[2];
    const float* ln_w  = (const float*)d_in[3];
    const float* ln_b  = (const float*)d_in[4];
    const float* pw_w  = (const float*)d_in[5];
    const float* q_w   = (const float*)d_in[6];
    const float* q_b   = (const float*)d_in[7];
    const float* k_w   = (const float*)d_in[8];
    const float* k_b   = (const float*)d_in[9];
    const float* v_w   = (const float*)d_in[10];
    const float* v_b   = (const float*)d_in[11];
    const float* rpe   = (const float*)d_in[12];
    const float* gamma = (const float*)d_in[13];

    float* out0 = (float*)d_out;
    float* attn = out0 + (size_t)4 * 512 * 1024;

    char* w = (char*)d_ws;
    short*    xt   = (short*)w;                    // 4 MB
    short*    qwb  = (short*)(w + 4194304);
    short*    kwb  = (short*)(w + 4718592);
    short*    vwb  = (short*)(w + 5242880);
    short*    qbf  = (short*)(w + 5767168);        // 4 MB dense q
    short*    xsb  = (short*)(w + 9961472);        // 4 MB
    short*    kfr  = (short*)(w + 14155776);       // 4 MB frag-ordered K
    short*    vfr  = (short*)(w + 18350080);       // 4 MB frag-ordered V (f16)
    float*    pos  = (float*)(w + 22544384);       // 32 KB
    uint2*    rpet = (uint2*)(w + 22577152);       // 8*4096*8 = 256 KB quad table

    prep_x<<<dim3(16, 8, 6), 256, 0, stream>>>(x, xt, q_w, k_w, v_w, qwb, kwb,
                                               vwb, rpe, rpet);
    gemm_q<<<dim3(64, 4), 256, 0, stream>>>(xt, qwb, q_b, qbf);
    offset_sample<<<4096, 256, 0, stream>>>(qbf, dw_w, dw_b, ln_w, ln_b, pw_w,
                                            xt, pos, xsb);
    gemm_kv<<<512, 256, 0, stream>>>(xsb, kwb, k_b, kfr, vwb, v_b, vfr);
    attn_fused<<<2048, 512, 0, stream>>>(qbf, kfr, vfr, pos, rpet, x,
                                         gamma, attn, out0);
}

// Round 18
// 107.276 us; speedup vs baseline: 1.0442x; 1.0024x over previous
//
#include <hip/hip_runtime.h>
#include <hip/hip_bf16.h>
#include <math.h>

typedef short bf16x8 __attribute__((ext_vector_type(8)));
typedef _Float16 f16x8 __attribute__((ext_vector_type(8)));
typedef float f32x4 __attribute__((ext_vector_type(4)));
typedef _Float16 h2 __attribute__((ext_vector_type(2)));

__device__ inline short f2bf(float f) {
    union { float f; unsigned u; } v; v.f = f;
    unsigned r = v.u + 0x7FFFu + ((v.u >> 16) & 1u);
    return (short)(r >> 16);
}
__device__ inline float bf2f(short s) {
    union { unsigned u; float f; } v; v.u = ((unsigned)(unsigned short)s) << 16;
    return v.f;
}
__device__ inline h2 pkrtz(float a, float b) {
    return __builtin_bit_cast(h2, __builtin_amdgcn_cvt_pkrtz(a, b));
}
__device__ inline float fast_exp2(float x) {
    float r;
    asm("v_exp_f32 %0, %1" : "=v"(r) : "v"(x));
    return r;
}
__device__ inline float dot2(h2 a, h2 b) {
#if __has_builtin(__builtin_amdgcn_fdot2)
    return __builtin_amdgcn_fdot2(a, b, 0.f, false);
#else
    return (float)a[0] * (float)b[0] + (float)a[1] * (float)b[1];
#endif
}
__device__ inline void nt_store4(float4 v, float* p) {
    __builtin_nontemporal_store(__builtin_bit_cast(f32x4, v), (f32x4*)p);
}

// ---------------------------------------------------------------------------
// z<4: transpose-cast x -> xt [b][p][c] bf16.  z==4: weight cast.
// z==5 (x<8,y==0): per-head 64x64 QUAD RPE table (4 bilinear taps packed as
// 4xf16 in 8B, pre-scaled by log2e).
// ---------------------------------------------------------------------------
__global__ __launch_bounds__(256) void prep_x(
    const float* __restrict__ x, short* __restrict__ xt,
    const float* __restrict__ qw, const float* __restrict__ kw,
    const float* __restrict__ vw, short* __restrict__ qwb,
    short* __restrict__ kwb, short* __restrict__ vwb,
    const float* __restrict__ rpe, uint2* __restrict__ rpet)
{
    __shared__ float ts[64][65];
    int t = threadIdx.x;
    if (blockIdx.z == 5) {   // quad RPE plane: head = blockIdx.x
        if (blockIdx.y != 0 || blockIdx.x >= 8) return;
        int hh = blockIdx.x;
        const float* rh = rpe + hh * 3969;
        const float L2E = 1.44269504f;
        auto P = [&](int y, int xx) -> float {
            return (y >= 1 && y <= 63 && xx >= 1 && xx <= 63)
                 ? rh[(y - 1) * 63 + (xx - 1)] * L2E : 0.f;
        };
        #pragma unroll
        for (int i = 0; i < 16; ++i) {
            int j = i * 256 + t;          // j < 4096
            int qy = j >> 6, qx = j & 63;
            h2 lo, hi;
            lo[0] = (_Float16)P(qy, qx);     lo[1] = (_Float16)P(qy, qx + 1);
            hi[0] = (_Float16)P(qy + 1, qx); hi[1] = (_Float16)P(qy + 1, qx + 1);
            uint2 w;
            w.x = __builtin_bit_cast(unsigned, lo);
            w.y = __builtin_bit_cast(unsigned, hi);
            rpet[hh * 4096 + j] = w;
        }
        return;
    }
    if (blockIdx.z == 4) {   // weight cast plane
        int f = blockIdx.y * 16 + blockIdx.x;
        int base = (f * 256 + t) * 8;
        #pragma unroll
        for (int w = 0; w < 3; ++w) {
            const float* src = (w == 0) ? qw : (w == 1) ? kw : vw;
            short* dst = (w == 0) ? qwb : (w == 1) ? kwb : vwb;
            float4 f0 = *(const float4*)(src + base);
            float4 f1 = *(const float4*)(src + base + 4);
            bf16x8 o;
            o[0] = f2bf(f0.x); o[1] = f2bf(f0.y); o[2] = f2bf(f0.z); o[3] = f2bf(f0.w);
            o[4] = f2bf(f1.x); o[5] = f2bf(f1.y); o[6] = f2bf(f1.z); o[7] = f2bf(f1.w);
            *(bf16x8*)(dst + base) = o;
        }
        return;
    }
    int p0 = blockIdx.x * 64, c0 = blockIdx.y * 64, b = blockIdx.z;
    #pragma unroll
    for (int i = 0; i < 16; ++i) {
        int idx = i * 256 + t;
        int cl = idx >> 6, pl = idx & 63;
        ts[cl][pl] = x[((size_t)(b * 512 + c0 + cl)) * 1024 + p0 + pl];
    }
    __syncthreads();
    #pragma unroll
    for (int i = 0; i < 16; ++i) {
        int idx = i * 256 + t;
        int pl = idx >> 6, cl = idx & 63;
        xt[((size_t)(b * 1024 + p0 + pl)) * 512 + c0 + cl] = f2bf(ts[cl][pl]);
    }
}

// ---------------------------------------------------------------------------
// 64x128 NT MFMA tile body (K=512): acc[2][4] per thread; 12 KB LDS.
// ---------------------------------------------------------------------------
__device__ inline void nt_tile_64x128(const short* __restrict__ A,
                                      const short* __restrict__ B,
                                      int m0, int n0, int t,
                                      short (*As)[32], short (*Bs)[32],
                                      f32x4 (&acc)[2][4])
{
    int wid = t >> 6, l = t & 63;
    int wm = wid >> 1, wn = wid & 1;
    int srB = t >> 1, halfB = t & 1;
    int swB = (srB >> 1) & 3;
    int sB0 = (halfB * 2) ^ swB, sB1 = (halfB * 2 + 1) ^ swB;
    int srA = t >> 2, qA = t & 3;
    int sA = qA ^ ((srA >> 1) & 3);
    for (int k0 = 0; k0 < 512; k0 += 32) {
        const int4 a0 = *(const int4*)(A + (size_t)(m0 + srA) * 512 + k0 + qA * 8);
        const int4 b0 = *(const int4*)(B + (size_t)(n0 + srB) * 512 + k0 + halfB * 16);
        const int4 b1 = *(const int4*)(B + (size_t)(n0 + srB) * 512 + k0 + halfB * 16 + 8);
        __syncthreads();
        *(int4*)&As[srA][sA * 8] = a0;
        *(int4*)&Bs[srB][sB0 * 8] = b0;
        *(int4*)&Bs[srB][sB1 * 8] = b1;
        __syncthreads();
        bf16x8 af[2], bfr[4];
        #pragma unroll
        for (int mt = 0; mt < 2; ++mt) {
            int r = wm * 32 + mt * 16 + (l & 15);
            af[mt] = *(const bf16x8*)&As[r][(((l >> 4)) ^ ((r >> 1) & 3)) * 8];
        }
        #pragma unroll
        for (int nt = 0; nt < 4; ++nt) {
            int r = wn * 64 + nt * 16 + (l & 15);
            bfr[nt] = *(const bf16x8*)&Bs[r][(((l >> 4)) ^ ((r >> 1) & 3)) * 8];
        }
        #pragma unroll
        for (int mt = 0; mt < 2; ++mt)
            #pragma unroll
            for (int nt = 0; nt < 4; ++nt)
                acc[mt][nt] = __builtin_amdgcn_mfma_f32_16x16x32_bf16(
                    af[mt], bfr[nt], acc[mt][nt], 0, 0, 0);
    }
}

// q projection (dense [m][n] bf16 out); grid (64, 4) = 256 blocks
__global__ __launch_bounds__(256) void gemm_q(
    const short* __restrict__ A, const short* __restrict__ B,
    const float* __restrict__ bias, short* __restrict__ Ob)
{
    __shared__ short As[64][32];
    __shared__ short Bs[128][32];
    int m0 = blockIdx.x * 64, n0 = blockIdx.y * 128;
    int t = threadIdx.x, wid = t >> 6, l = t & 63;
    int wm = wid >> 1, wn = wid & 1;
    f32x4 acc[2][4] = {};
    nt_tile_64x128(A, B, m0, n0, t, As, Bs, acc);
    #pragma unroll
    for (int mt = 0; mt < 2; ++mt)
        #pragma unroll
        for (int nt = 0; nt < 4; ++nt)
            #pragma unroll
            for (int r = 0; r < 4; ++r) {
                int m = m0 + wm * 32 + mt * 16 + (l >> 4) * 4 + r;
                int n = n0 + wn * 64 + nt * 16 + (l & 15);
                Ob[(size_t)m * 512 + n] = f2bf(acc[mt][nt][r] + bias[n]);
            }
}

// k-gemm (bid<256, SWAPPED: D[channel][sample]) + v-gemm (bid>=256, SWAPPED:
// D[sample][channel]); coalesced uint2 fragment-order stores.
__global__ __launch_bounds__(256) void gemm_kv(
    const short* __restrict__ xsb, const short* __restrict__ kwb,
    const float* __restrict__ k_b, short* __restrict__ kfr,
    const short* __restrict__ vwb, const float* __restrict__ v_b,
    short* __restrict__ vfr)
{
    __shared__ short As[64][32];
    __shared__ short Bs[128][32];
    int bid = blockIdx.x;
    int t = threadIdx.x, wid = t >> 6, l = t & 63;
    int wm = wid >> 1, wn = wid & 1;
    f32x4 acc[2][4] = {};
    if (bid < 256) {
        int m0 = (bid >> 5) * 64, n0 = (bid & 31) * 128;
        nt_tile_64x128(kwb, xsb, m0, n0, t, As, Bs, acc);
        int h = m0 >> 6;
        #pragma unroll
        for (int mt = 0; mt < 2; ++mt) {
            int ch0 = m0 + wm * 32 + mt * 16 + (l >> 4) * 4;
            float4 kb4 = *(const float4*)(k_b + ch0);
            int frag = (ch0 >> 5) & 1, gg = (ch0 >> 3) & 3, e = ch0 & 7;
            #pragma unroll
            for (int nt = 0; nt < 4; ++nt) {
                int sm = n0 + wn * 64 + nt * 16 + (l & 15);
                int bq = sm >> 10, p = sm & 1023;
                int T = p >> 4, cs = p & 15;
                uint2 w;
                w.x = (unsigned)(unsigned short)f2bf(acc[mt][nt][0] + kb4.x)
                    | ((unsigned)(unsigned short)f2bf(acc[mt][nt][1] + kb4.y) << 16);
                w.y = (unsigned)(unsigned short)f2bf(acc[mt][nt][2] + kb4.z)
                    | ((unsigned)(unsigned short)f2bf(acc[mt][nt][3] + kb4.w) << 16);
                *(uint2*)(kfr + ((((size_t)(bq * 8 + h) * 64 + T) * 2 + frag) * 64
                                 + gg * 16 + cs) * 8 + e) = w;
            }
        }
    } else {
        int id2 = bid - 256;
        int z = id2 >> 6, rr2 = id2 & 63;
        int m0 = (rr2 >> 2) * 64, n0 = (rr2 & 3) * 128;
        nt_tile_64x128(xsb + (size_t)z * 524288, vwb, m0, n0, t, As, Bs, acc);
        #pragma unroll
        for (int mt = 0; mt < 2; ++mt) {
            int p0 = m0 + wm * 32 + mt * 16 + (l >> 4) * 4;
            int cc = p0 >> 5, gg = (p0 >> 3) & 3, e = p0 & 7;
            #pragma unroll
            for (int nt = 0; nt < 4; ++nt) {
                int ch = n0 + wn * 64 + nt * 16 + (l & 15);
                int h = ch >> 6, wg = (ch & 63) >> 4, cs = ch & 15;
                float vb = v_b[ch];
                h2 plo, phi;
                plo[0] = (_Float16)(acc[mt][nt][0] + vb);
                plo[1] = (_Float16)(acc[mt][nt][1] + vb);
                phi[0] = (_Float16)(acc[mt][nt][2] + vb);
                phi[1] = (_Float16)(acc[mt][nt][3] + vb);
                uint2 w;
                w.x = __builtin_bit_cast(unsigned, plo);
                w.y = __builtin_bit_cast(unsigned, phi);
                *(uint2*)(vfr + ((((size_t)(z * 8 + h) * 4 + wg) * 32 + cc) * 64
                                 + gg * 16 + cs) * 8 + e) = w;
            }
        }
    }
}

// ---------------------------------------------------------------------------
// FUSED offset network + deformable sampling
// ---------------------------------------------------------------------------
__global__ __launch_bounds__(256) void offset_sample(
    const short* __restrict__ qbf, const float* __restrict__ dw_w,
    const float* __restrict__ dw_b, const float* __restrict__ ln_w,
    const float* __restrict__ ln_b, const float* __restrict__ pw_w,
    const short* __restrict__ xt, float* __restrict__ pos,
    short* __restrict__ xs)
{
    __shared__ float red[8];
    __shared__ float2 psh;
    int bid = blockIdx.x;
    int b = bid >> 10, p = bid & 1023;
    int y = p >> 5, x = p & 31;
    int t = threadIdx.x;
    int c0 = 2 * t;
    const short* qb = qbf + (size_t)b * 524288;
    float h0, h1;
    {
        const float* w0 = dw_w + c0 * 9;
        const float* w1 = w0 + 9;
        float s0 = 0.f, s1 = 0.f;
        #pragma unroll
        for (int ky = 0; ky < 3; ++ky) {
            int yy = y + ky - 1;
            if (yy < 0 || yy > 31) continue;
            #pragma unroll
            for (int kx = 0; kx < 3; ++kx) {
                int xx = x + kx - 1;
                if (xx < 0 || xx > 31) continue;
                unsigned u = *(const unsigned*)(qb + (size_t)(yy * 32 + xx) * 512 + c0);
                s0 += bf2f((short)(u & 0xFFFF)) * w0[ky * 3 + kx];
                s1 += bf2f((short)(u >> 16)) * w1[ky * 3 + kx];
            }
        }
        float2 db = *(const float2*)(dw_b + c0);
        h0 = s0 + db.x; h1 = s1 + db.y;
    }
    float ls = h0 + h1;
    float lq = h0 * h0 + h1 * h1;
    #pragma unroll
    for (int s = 32; s >= 1; s >>= 1) {
        ls += __shfl_xor(ls, s);
        lq += __shfl_xor(lq, s);
    }
    int wid = t >> 6, lane = t & 63;
    if (lane == 0) { red[wid] = ls; red[4 + wid] = lq; }
    __syncthreads();
    float mu  = (red[0] + red[1] + red[2] + red[3]) * (1.f / 512.f);
    float var = (red[4] + red[5] + red[6] + red[7]) * (1.f / 512.f) - mu * mu;
    float rstd = rsqrtf(var + 1e-5f);
    float o0, o1;
    {
        float2 lw = *(const float2*)(ln_w + c0);
        float2 lb = *(const float2*)(ln_b + c0);
        float2 p0 = *(const float2*)(pw_w + c0);
        float2 p1 = *(const float2*)(pw_w + 512 + c0);
        float hn0 = (h0 - mu) * rstd * lw.x + lb.x;
        float hn1 = (h1 - mu) * rstd * lw.y + lb.y;
        float g0 = 0.5f * hn0 * (1.f + erff(hn0 * 0.70710678118f));
        float g1 = 0.5f * hn1 * (1.f + erff(hn1 * 0.70710678118f));
        o0 = g0 * p0.x + g1 * p0.y;
        o1 = g0 * p1.x + g1 * p1.y;
    }
    #pragma unroll
    for (int s = 32; s >= 1; s >>= 1) {
        o0 += __shfl_xor(o0, s);
        o1 += __shfl_xor(o1, s);
    }
    __syncthreads();
    if (lane == 0) { red[wid] = o0; red[4 + wid] = o1; }
    __syncthreads();
    if (t == 0) {
        float oy = tanhf(red[0] + red[1] + red[2] + red[3]) * 0.0625f;
        float ox = tanhf(red[4] + red[5] + red[6] + red[7]) * 0.0625f;
        float ry = ((y + 0.5f) * (1.f / 32.f)) * 2.f - 1.f;
        float rx = ((x + 0.5f) * (1.f / 32.f)) * 2.f - 1.f;
        float py = oy + ry, px = ox + rx;
        pos[bid * 2]     = py;
        pos[bid * 2 + 1] = px;
        psh = make_float2(py, px);
    }
    __syncthreads();
    float py = psh.x, px = psh.y;
    float gx = (px + 1.f) * 15.5f;
    float gy = (py + 1.f) * 15.5f;
    float x0f = floorf(gx), y0f = floorf(gy);
    int ix0 = (int)x0f, iy0 = (int)y0f;
    float wx1 = gx - x0f, wx0 = 1.f - wx1;
    float wy1 = gy - y0f, wy0 = 1.f - wy1;
    const short* base = xt + (size_t)b * 524288;
    float a0 = 0.f, a1 = 0.f;
    #pragma unroll
    for (int tap = 0; tap < 4; ++tap) {
        int ix = ix0 + (tap & 1), iy = iy0 + (tap >> 1);
        float w = ((tap & 1) ? wx1 : wx0) * ((tap >> 1) ? wy1 : wy0);
        if (ix >= 0 && ix < 32 && iy >= 0 && iy < 32) {
            unsigned u = *(const unsigned*)(base + (size_t)(iy * 32 + ix) * 512 + c0);
            a0 += bf2f((short)(u & 0xFFFF)) * w;
            a1 += bf2f((short)(u >> 16)) * w;
        }
    }
    unsigned o = ((unsigned)(unsigned short)f2bf(a0)) |
                 (((unsigned)(unsigned short)f2bf(a1)) << 16);
    *(unsigned*)(xs + (size_t)bid * 512 + c0) = o;
}

// ---------------------------------------------------------------------------
// FUSED attention, 512 threads, swapped QK^T, FRAGMENT-ORDERED K/V,
// QUAD RPE table (1 ds_read_b64 per logit). launch_bounds(512,4).
// Stream: ALL 8 waves write attn rows via PLAIN (cached) float4 stores —
// A/B vs round 17's nontemporal (suspected to defeat L2 write combining).
// ---------------------------------------------------------------------------
__global__ __launch_bounds__(512, 4) void attn_fused(
    const short* __restrict__ qbf, const short* __restrict__ kfr,
    const short* __restrict__ vfr, const float* __restrict__ pos,
    const uint2* __restrict__ rpet, const float* __restrict__ x,
    const float* __restrict__ gamma, float* __restrict__ attn_out,
    float* __restrict__ out0)
{
    __shared__ __align__(16) char smem_raw[40960];
    uint2*  rpq    = (uint2*)smem_raw;                // [64*64] quad table
    float*  ccsf   = (float*)(smem_raw + 32768);      // [1024*2] (cy,cx) pairs
    short*  Pn     = (short*)smem_raw;                // [16][1032] f16 RAW exp
    float*  S_part = (float*)(smem_raw + 33536);      // [16][8]

    int bid = blockIdx.x;
    int xcd = bid & 7, seq = bid >> 3;
    int m0 = (seq & 63) * 16;
    int bh = xcd + 8 * (seq >> 6);          // h = bh & 7 == xcd
    int b = bh >> 3, h = bh & 7;
    int t = threadIdx.x, wn = t >> 6, l = t & 63;
    int g = l >> 4, c16 = l & 15;

    const uint2* rt = rpet + h * 4096;
    #pragma unroll
    for (int i = 0; i < 8; ++i)
        rpq[i * 512 + t] = rt[i * 512 + t];
    #pragma unroll
    for (int i = 0; i < 2; ++i) {
        int idx = i * 512 + t;
        float2 pf = *(const float2*)(pos + b * 2048 + idx * 2);
        ccsf[idx * 2]     = fmaf(-15.5f, pf.x, 32.f);
        ccsf[idx * 2 + 1] = fmaf(-15.5f, pf.y, 32.f);
    }
    // q fragments (dense layout; only 2 loads/thread)
    int rowm = m0 + c16;
    const short* qrow = qbf + ((size_t)(b * 1024 + rowm) * 512 + h * 64 + g * 8);
    bf16x8 aq0 = *(const bf16x8*)qrow;
    bf16x8 aq1 = *(const bf16x8*)(qrow + 32);
    float qy = (((rowm >> 5) + 0.5f) * (1.f / 16.f) - 1.f) * 15.5f;
    float qx = (((rowm & 31) + 0.5f) * (1.f / 16.f) - 1.f) * 15.5f;
    __syncthreads();

    // ---- pass A: 8 n-tiles; K frags coalesced + 2-deep register prefetch
    float Ssum = 0.f;
    float e0, e1;
    unsigned ep[16];
    const short* kr = kfr + (size_t)(bh * 64 + wn * 8) * 1024 + l * 8;
    bf16x8 ka0 = *(const bf16x8*)kr;
    bf16x8 kb0 = *(const bf16x8*)(kr + 512);
    bf16x8 ka1 = *(const bf16x8*)(kr + 1024);
    bf16x8 kb1 = *(const bf16x8*)(kr + 1536);
    #pragma unroll
    for (int nt = 0; nt < 8; ++nt) {
        bf16x8 bk0 = ka0, bk1 = kb0;
        ka0 = ka1; kb0 = kb1;
        if (nt < 6) {
            ka1 = *(const bf16x8*)(kr + (nt + 2) * 1024);
            kb1 = *(const bf16x8*)(kr + (nt + 2) * 1024 + 512);
        }
        __builtin_amdgcn_s_setprio(1);
        f32x4 acc = {0.f, 0.f, 0.f, 0.f};
        acc = __builtin_amdgcn_mfma_f32_16x16x32_bf16(bk0, aq0, acc, 0, 0, 0);
        acc = __builtin_amdgcn_mfma_f32_16x16x32_bf16(bk1, aq1, acc, 0, 0, 0);
        __builtin_amdgcn_s_setprio(0);
        int nb = wn * 128 + nt * 16;
        const float* cbase = ccsf + (nb + g * 4) * 2;
        float4 c01 = *(const float4*)cbase;        // (cy,cx) for r=0,1
        float4 c23 = *(const float4*)(cbase + 4);  // (cy,cx) for r=2,3
        #pragma unroll
        for (int r = 0; r < 4; ++r) {
            float cy = (r == 0) ? c01.x : (r == 1) ? c01.z : (r == 2) ? c23.x : c23.z;
            float cx = (r == 0) ? c01.y : (r == 1) ? c01.w : (r == 2) ? c23.y : c23.w;
            float gyp = qy + cy;
            float gxp = qx + cx;
            float fy = floorf(gyp), fx = floorf(gxp);
            float wy1 = gyp - fy, wx1 = gxp - fx;
            int ad = (int)(fy * 64.f + fx);
            uint2 q4 = rpq[ad];                      // all 4 taps, one b64
            h2 lo = __builtin_bit_cast(h2, q4.x);
            h2 hi = __builtin_bit_cast(h2, q4.y);
            h2 wp = pkrtz(1.f - wx1, wx1);
            float t0 = dot2(lo, wp);
            float t1 = dot2(hi, wp);
            float bias2 = t0 + wy1 * (t1 - t0);      // already x log2e
            float logit2 = fmaf(acc[r], 0.1803368801f, bias2);  // 0.125*log2e
            float e = fast_exp2(logit2);
            Ssum += e;
            if (r == 0) e0 = e;
            else if (r == 1) ep[nt * 2] = __builtin_bit_cast(unsigned, pkrtz(e0, e));
            else if (r == 2) e1 = e;
            else ep[nt * 2 + 1] = __builtin_bit_cast(unsigned, pkrtz(e1, e));
        }
    }
    Ssum += __shfl_xor(Ssum, 16);
    Ssum += __shfl_xor(Ssum, 32);
    __syncthreads();   // ALL pass-A LDS reads retired; quad/ccs region dead
    if (l < 16) S_part[c16 * 8 + wn] = Ssum;
    // ---- raw exp pairs -> Pn[m=c16][n]
    short* prow = Pn + c16 * 1032 + wn * 128;
    #pragma unroll
    for (int nt = 0; nt < 8; ++nt) {
        uint2 w;
        w.x = ep[nt * 2];
        w.y = ep[nt * 2 + 1];
        *(uint2*)(prow + nt * 16 + g * 4) = w;
    }
    __syncthreads();
    float4 sa = *(const float4*)&S_part[c16 * 8];
    float4 sb = *(const float4*)&S_part[c16 * 8 + 4];
    float invS = 1.f / (sa.x + sa.y + sa.z + sa.w + sb.x + sb.y + sb.z + sb.w);

    size_t obase = ((size_t)(bh * 1024 + m0)) * 1024;
    // ---- stream: ALL 8 waves; wave wn owns rows 2wn, 2wn+1 (4 x 256-col
    //      quarters each, coalesced PLAIN float4 stores)
    #pragma unroll
    for (int rr = 0; rr < 2; ++rr) {
        int row = wn * 2 + rr;
        float ivr = __shfl(invS, row);
        #pragma unroll
        for (int qq = 0; qq < 4; ++qq) {
            int col = qq * 256 + l * 4;
            uint2 pr8 = *(const uint2*)(Pn + row * 1032 + col);
            h2 a = __builtin_bit_cast(h2, pr8.x);
            h2 bb = __builtin_bit_cast(h2, pr8.y);
            float4 vv = make_float4((float)a[0] * ivr, (float)a[1] * ivr,
                                    (float)bb[0] * ivr, (float)bb[1] * ivr);
            *(float4*)(attn_out + obase + (size_t)row * 1024 + col) = vv;
        }
    }
    if (wn < 4) {
        // ---- PV: wave wn owns channels wn*16..+15; V fragment-ordered
        const short* Vb = vfr + (size_t)((bh * 4 + wn) * 32) * 512;
        const short* Prow = Pn + c16 * 1032 + g * 8;
        f32x4 dacc = {0.f, 0.f, 0.f, 0.f};
        __builtin_amdgcn_s_setprio(1);
        #pragma unroll
        for (int cc = 0; cc < 32; ++cc) {
            f16x8 pa  = *(const f16x8*)(Prow + cc * 32);
            f16x8 vb8 = *(const f16x8*)(Vb + cc * 512 + l * 8);
            dacc = __builtin_amdgcn_mfma_f32_16x16x32_f16(pa, vb8, dacc, 0, 0, 0);
        }
        __builtin_amdgcn_s_setprio(0);
        float gm = gamma[0];
        float gi0 = gm * __shfl(invS, g * 4);
        float gi1 = gm * __shfl(invS, g * 4 + 1);
        float gi2 = gm * __shfl(invS, g * 4 + 2);
        float gi3 = gm * __shfl(invS, g * 4 + 3);
        int ch = h * 64 + wn * 16 + c16;
        int m = m0 + g * 4;
        size_t idx = ((size_t)(b * 512 + ch)) * 1024 + m;
        float4 xv = *(const float4*)(x + idx);
        float4 ov;
        ov.x = gi0 * dacc[0] + xv.x;
        ov.y = gi1 * dacc[1] + xv.y;
        ov.z = gi2 * dacc[2] + xv.z;
        ov.w = gi3 * dacc[3] + xv.w;
        nt_store4(ov, out0 + idx);
    }
}

extern "C" void kernel_launch(void* const* d_in, const int* in_sizes, int n_in,
                              void* d_out, int out_size, void* d_ws, size_t ws_size,
                              hipStream_t stream) {
    const float* x     = (const float*)d_in[0];
    const float* dw_w  = (const float*)d_in[1];
    const float* dw_b  = (const float*)d_in[2];
    const float* ln_w  = (const float*)d_in[3];
    const float* ln_b  = (const float*)d_in[4];
    const float* pw_w  = (const float*)d_in[5];
    const float* q_w   = (const float*)d_in[6];
    const float* q_b   = (const float*)d_in[7];
    const float* k_w   = (const float*)d_in[8];
    const float* k_b   = (const float*)d_in[9];
    const float* v_w   = (const float*)d_in[10];
    const float* v_b   = (const float*)d_in[11];
    const float* rpe   = (const float*)d_in[12];
    const float* gamma = (const float*)d_in[13];

    float* out0 = (float*)d_out;
    float* attn = out0 + (size_t)4 * 512 * 1024;

    char* w = (char*)d_ws;
    short*    xt   = (short*)w;                    // 4 MB
    short*    qwb  = (short*)(w + 4194304);
    short*    kwb  = (short*)(w + 4718592);
    short*    vwb  = (short*)(w + 5242880);
    short*    qbf  = (short*)(w + 5767168);        // 4 MB dense q
    short*    xsb  = (short*)(w + 9961472);        // 4 MB
    short*    kfr  = (short*)(w + 14155776);       // 4 MB frag-ordered K
    short*    vfr  = (short*)(w + 18350080);       // 4 MB frag-ordered V (f16)
    float*    pos  = (float*)(w + 22544384);       // 32 KB
    uint2*    rpet = (uint2*)(w + 22577152);       // 8*4096*8 = 256 KB quad table

    prep_x<<<dim3(16, 8, 6), 256, 0, stream>>>(x, xt, q_w, k_w, v_w, qwb, kwb,
                                               vwb, rpe, rpet);
    gemm_q<<<dim3(64, 4), 256, 0, stream>>>(xt, qwb, q_b, qbf);
    offset_sample<<<4096, 256, 0, stream>>>(qbf, dw_w, dw_b, ln_w, ln_b, pw_w,
                                            xt, pos, xsb);
    gemm_kv<<<512, 256, 0, stream>>>(xsb, kwb, k_b, kfr, vwb, v_b, vfr);
    attn_fused<<<2048, 512, 0, stream>>>(qbf, kfr, vfr, pos, rpet, x,
                                         gamma, attn, out0);
}